// Round 4
// baseline (6414.832 us; speedup 1.0000x reference)
//
#include <hip/hip_runtime.h>
#include <stdint.h>

// ---------------------------------------------------------------------------
// EditorActorCritic: embed GEMM -> input-proj GEMM -> clustered LSTM scan ->
// actor/critic head GEMMs.  fp32/bf16 input dtype detected at runtime;
// compute is bf16 MFMA, fp32 accumulate.
// Round-10: release/acquire FLAG exchange.  Mechanism finding from rounds
// 1-3: RELAXED agent-scope polling loads can be served from a stale L2 line
// indefinitely (no invalidate) -> poll advances at cache-eviction pace
// (3.5us/step steady, 31.9ms outlier).  Fix is the canonical protocol:
// plain data stores -> __syncthreads (drains vmcnt) -> ONE release-agent
// flag store per WG (emits L2 writeback); reader spins on ONE acquire-agent
// flag word (each load emits the invalidate -> staleness impossible), then
// plain-loads the 4KB peer half once.  2 ranks/cluster, Wh register-pinned,
// K-loop split around the poll (own half before, peer half after).
// ---------------------------------------------------------------------------

typedef short v8s __attribute__((ext_vector_type(8)));   // 8 x bf16 bits (MFMA A/B frag)
typedef float v4f __attribute__((ext_vector_type(4)));   // MFMA C/D frag
typedef unsigned short u16x4 __attribute__((ext_vector_type(4)));

#define DEV static __device__ __forceinline__
#define DT_THRESH 4096

DEV float b2f(unsigned short h) {
    union { unsigned int u; float f; } v; v.u = ((unsigned int)h) << 16; return v.f;
}
DEV unsigned short f2b(float f) {
    union { float f; unsigned int u; } v; v.f = f;
    unsigned int u = v.u;
    return (unsigned short)((u + 0x7fffu + ((u >> 16) & 1u)) >> 16);
}
DEV float sigf(float x) {
    x = fminf(fmaxf(x, -30.f), 30.f);
    return 1.f / (1.f + __expf(-x));
}
DEV float tanh_(float x) {
    x = fminf(fmaxf(x, -15.f), 15.f);
    float e = __expf(-2.f * x);
    return (1.f - e) / (1.f + e);
}

// ---------------------------------------------------------------------------
// K0a: dones decode (robust int32/bf16/byte) + zero dtype flag + exchange flags.
// ---------------------------------------------------------------------------
__global__ __launch_bounds__(1024) void dones_k(const void* __restrict__ raw,
                                                int* __restrict__ dst,
                                                int* __restrict__ dt,
                                                unsigned int* __restrict__ flg) {
    __shared__ int bad_int, bad_bf;
    int tid = threadIdx.x;
    if (tid == 0) { bad_int = 0; bad_bf = 0; dt[0] = 0; }
    // clear exchange flags (2 parities x 16 clusters x 2 ranks, 32-dword stride)
    for (int i = tid; i < 2048; i += 1024) flg[i] = 0u;
    __syncthreads();
    const unsigned int* w = (const unsigned int*)raw;
    int li = 0, lb = 0;
    for (int i = tid; i < 32768; i += 1024) {
        unsigned int v = w[i];
        if (v > 1u) li = 1;
        unsigned int h0 = v & 0xffffu, h1 = v >> 16;
        if ((h0 != 0u && h0 != 0x3f80u) || (h1 != 0u && h1 != 0x3f80u)) lb = 1;
    }
    if (li) atomicOr(&bad_int, 1);
    if (lb) atomicOr(&bad_bf, 1);
    __syncthreads();
    int mode = (!bad_int) ? 0 : ((!bad_bf) ? 1 : 2);
    for (int e = tid; e < 131072; e += 1024) {
        int v;
        if (mode == 0)      v = (((const int*)raw)[e] != 0);
        else if (mode == 1) v = (((const unsigned short*)raw)[e] != 0);
        else                v = (((const unsigned char*)raw)[e] != 0);
        dst[e] = v;
    }
}

// ---------------------------------------------------------------------------
// K0b: float-dtype detect.
// ---------------------------------------------------------------------------
__global__ __launch_bounds__(256) void detect_k(const unsigned short* __restrict__ xr,
                                                int* __restrict__ dt) {
    int tid = blockIdx.x * 256 + threadIdx.x;   // 16384 threads
    int cnt = 0;
    for (int i = tid; i < (1 << 24); i += 16384) {
        unsigned int e = (xr[i] >> 7) & 0xffu;
        cnt += (e >= 140u);
    }
    for (int o = 32; o; o >>= 1) cnt += __shfl_down(cnt, o);
    if ((threadIdx.x & 63) == 0 && cnt) atomicAdd(dt, cnt);
}

// ---------------------------------------------------------------------------
// K0c: x -> bf16 canonical copy.
// ---------------------------------------------------------------------------
__global__ __launch_bounds__(256) void cvt_x_k(const void* __restrict__ xr,
                                               unsigned short* __restrict__ xb,
                                               const int* __restrict__ dt) {
    int fp32i = dt[0] > DT_THRESH;
    long i4 = (long)blockIdx.x * 256 + threadIdx.x;
    if (fp32i) {
        float4 v = ((const float4*)xr)[i4];
        uint2 p;
        p.x = (unsigned int)f2b(v.x) | ((unsigned int)f2b(v.y) << 16);
        p.y = (unsigned int)f2b(v.z) | ((unsigned int)f2b(v.w) << 16);
        ((uint2*)xb)[i4] = p;
    } else {
        ((uint2*)xb)[i4] = ((const uint2*)xr)[i4];
    }
}

// ---------------------------------------------------------------------------
// K0d: transpose (and dtype-convert) weight matrices W[R][C] -> WT[C][R] bf16.
// ---------------------------------------------------------------------------
struct TransArgs {
    const void* src[9];
    unsigned short* dst[9];
    int R[9];
    int C[9];
    int prefix[10];
    int total;
};

__global__ __launch_bounds__(256) void trans_kernel(TransArgs a, const int* __restrict__ dt) {
    int fp32i = dt[0] > DT_THRESH;
    int id = blockIdx.x * 256 + threadIdx.x;
    if (id >= a.total) return;
    int m = 0;
#pragma unroll
    for (int k = 0; k < 9; k++)
        if (id >= a.prefix[k + 1]) m = k + 1;
    int e = id - a.prefix[m];
    int C = a.C[m];
    int r = e / C, c = e % C;
    unsigned short v;
    if (fp32i) v = f2b(((const float*)a.src[m])[e]);
    else       v = ((const unsigned short*)a.src[m])[e];
    a.dst[m][c * a.R[m] + r] = v;
}

// ---------------------------------------------------------------------------
// Generic bf16 GEMM (verified since round 3).
// ---------------------------------------------------------------------------
template <int TN, int ACT, int OM>
__global__ __launch_bounds__(256) void gemm_k(const unsigned short* __restrict__ A,
                                              const unsigned short* __restrict__ BT,
                                              const unsigned short* __restrict__ bias,
                                              void* __restrict__ Cout, long coff,
                                              const int* __restrict__ dtf,
                                              int N, int K) {
    __shared__ unsigned short As[128][40];
    __shared__ unsigned short Bs[TN][40];
    const int tid = threadIdx.x;
    const int l = tid & 63, w = tid >> 6;
    const long m0 = (long)blockIdx.x * 128;
    const int n0 = blockIdx.y * TN;
    constexpr int NRT = (TN == 128) ? 4 : 2;
    constexpr int NCT = (TN == 128) ? 4 : 1;
    int fp32o = (OM == 1) ? (dtf[0] > DT_THRESH) : 0;

    v4f acc[NRT][NCT];
    for (int i = 0; i < NRT; i++)
        for (int j = 0; j < NCT; j++) acc[i][j] = v4f{0.f, 0.f, 0.f, 0.f};

    for (int kc = 0; kc < K; kc += 32) {
        {
            int row = tid >> 1, part = tid & 1;
            const uint4* src = (const uint4*)(A + (m0 + row) * K + kc + part * 16);
            uint4 v0 = src[0], v1 = src[1];
            *(uint4*)&As[row][part * 16] = v0;
            *(uint4*)&As[row][part * 16 + 8] = v1;
        }
        if (TN == 128) {
            int row = tid >> 1, part = tid & 1;
            const uint4* src = (const uint4*)(BT + (long)(n0 + row) * K + kc + part * 16);
            uint4 v0 = src[0], v1 = src[1];
            *(uint4*)&Bs[row][part * 16] = v0;
            *(uint4*)&Bs[row][part * 16 + 8] = v1;
        } else if (tid < 32) {
            int row = tid >> 1, part = tid & 1;
            const uint4* src = (const uint4*)(BT + (long)(n0 + row) * K + kc + part * 16);
            uint4 v0 = src[0], v1 = src[1];
            *(uint4*)&Bs[row][part * 16] = v0;
            *(uint4*)&Bs[row][part * 16 + 8] = v1;
        }
        __syncthreads();

        v8s af[NRT], bf[NCT];
#pragma unroll
        for (int i = 0; i < NRT; i++) {
            int rt = (TN == 128) ? ((w >> 1) * 4 + i) : (w * 2 + i);
            af[i] = *(const v8s*)&As[rt * 16 + (l & 15)][(l >> 4) * 8];
        }
#pragma unroll
        for (int j = 0; j < NCT; j++) {
            int ct = (TN == 128) ? ((w & 1) * 4 + j) : 0;
            bf[j] = *(const v8s*)&Bs[ct * 16 + (l & 15)][(l >> 4) * 8];
        }
#pragma unroll
        for (int i = 0; i < NRT; i++)
#pragma unroll
            for (int j = 0; j < NCT; j++)
                acc[i][j] = __builtin_amdgcn_mfma_f32_16x16x32_bf16(af[i], bf[j], acc[i][j], 0, 0, 0);
        __syncthreads();
    }

#pragma unroll
    for (int j = 0; j < NCT; j++) {
        int ct = (TN == 128) ? ((w & 1) * 4 + j) : 0;
        int col = ct * 16 + (l & 15);
        float bv = b2f(bias[n0 + col]);
#pragma unroll
        for (int i = 0; i < NRT; i++) {
            int rt = (TN == 128) ? ((w >> 1) * 4 + i) : (w * 2 + i);
#pragma unroll
            for (int q = 0; q < 4; q++) {
                long row = m0 + rt * 16 + (l >> 4) * 4 + q;
                float v = acc[i][j][q] + bv;
                if (ACT == 1) v = fmaxf(v, 0.f);
                if (ACT == 2) v = tanh_(v);
                long idx = coff + row * (long)N + n0 + col;
                if (OM == 1 && fp32o) ((float*)Cout)[idx] = v;
                else ((unsigned short*)Cout)[idx] = f2b(v);
            }
        }
    }
}

// ---------------------------------------------------------------------------
// K2: LSTM scan.  16 clusters x 2 ranks = 32 WGs of 512 threads (8 waves).
// Rank r: hid cols [r*128, r*128+128), Wh B-frags register-pinned (128
// VGPR/lane).  Exchange protocol per step: plain uint2 data stores ->
// __syncthreads (drains vmcnt per wave) -> tid0 RELEASE-agent flag store
// (L2 writeback); reader spins on ACQUIRE-agent flag (invalidate per load,
// staleness impossible), then plain-loads the 4KB peer half.  K-loop split:
// own half before the poll, peer half after.  Update path: thread owns 4
// consecutive hid at one row (row=tid>>5, hid0=(tid&31)*4) -> vectorized
// publish/history stores, one dones load per thread.
// ---------------------------------------------------------------------------
__global__ __launch_bounds__(512, 2) void lstm_k(const unsigned short* __restrict__ xz,   // [512*256][1024]
                                                 const int* __restrict__ dones,           // [512][256] decoded
                                                 const void* __restrict__ h0c,
                                                 const void* __restrict__ h0h,
                                                 const unsigned short* __restrict__ WhT,  // [1024][256]
                                                 unsigned int* __restrict__ flg,          // 2048 dwords
                                                 unsigned int* __restrict__ hd32,         // data: 2x16x2x1024 dw
                                                 unsigned short* __restrict__ hs,         // [512*256][256] (bf16)
                                                 void* __restrict__ outv,
                                                 const int* __restrict__ dtf) {
    __shared__ unsigned short hlds[16][256];   // full-h tile, XOR-swizzled cols
    __shared__ float zlds[4][16][132];         // [gate][row][hid] (+4 pad)

    const int tid = threadIdx.x;               // 0..511
    const int l = tid & 63;
    const int w = tid >> 6;                    // wave 0..7
    const int cluster = blockIdx.x & 15;
    const int r = blockIdx.x >> 4;             // rank 0..1
    const int p = r ^ 1;                       // peer rank
    const int bt = cluster * 16;
    const int fp32o = dtf[0] > DT_THRESH;
    const int gate = w & 3;
    const int hblk = (w >> 2) * 64;            // hid sub-block within rank's 128
    const int l15 = l & 15;
    const int lq = l >> 4;
    const int row = tid >> 5;                  // update-path row (0..15)
    const int hid0 = (tid & 31) * 4;           // rank-local hid base (0..124)
    const int swz = (row & 7) * 8;

    // ---- Wh B-fragments -> registers (once): bw[j][ks], 128 VGPRs
    v8s bw[4][8];
#pragma unroll
    for (int j = 0; j < 4; j++) {
        const unsigned short* wp =
            WhT + (long)(gate * 256 + r * 128 + hblk + j * 16 + l15) * 256 + lq * 8;
#pragma unroll
        for (int ks = 0; ks < 8; ks++) bw[j][ks] = *(const v8s*)(wp + ks * 32);
    }

    // ---- init: c/h0 load (4 consecutive hid at one row), masked publish
    float c[4], hcur[4] = {0.f, 0.f, 0.f, 0.f};
    int dn_cur = dones[bt + row];
    int dn_nxt = dones[256 + bt + row];
    {
        u16x4 hw4;
#pragma unroll
        for (int i = 0; i < 4; i++) {
            long idx = (long)(bt + row) * 256 + r * 128 + hid0 + i;
            c[i] = fp32o ? ((const float*)h0c)[idx] : b2f(((const unsigned short*)h0c)[idx]);
            float h0 = fp32o ? ((const float*)h0h)[idx] : b2f(((const unsigned short*)h0h)[idx]);
            hw4[i] = dn_cur ? (unsigned short)0 : f2b(h0);
        }
        *(u16x4*)&hlds[row][(r * 128 + hid0) ^ swz] = hw4;
        int mb = ((0 * 16 + cluster) * 2 + r) * 1024 + row * 64 + (tid & 31) * 2;
        hd32[mb]     = (unsigned int)hw4[0] | ((unsigned int)hw4[1] << 16);
        hd32[mb + 1] = (unsigned int)hw4[2] | ((unsigned int)hw4[3] << 16);
    }
    // xz prefetch for t=0 (per-wave MFMA-C-layout mapping)
    unsigned short xzp[16];
#pragma unroll
    for (int j = 0; j < 4; j++)
#pragma unroll
        for (int q = 0; q < 4; q++)
            xzp[j * 4 + q] = xz[(long)(bt + lq * 4 + q) * 1024 +
                                (gate * 256 + r * 128 + hblk + j * 16 + l15)];
    __syncthreads();   // data stores drained (vmcnt) + hlds visible
    if (tid == 0)
        __hip_atomic_store(&flg[((0 * 16 + cluster) * 2 + r) * 32], 1u,
                           __ATOMIC_RELEASE, __HIP_MEMORY_SCOPE_AGENT);

    int dead = 0;

    for (int t = 0; t < 512; t++) {
        const int par = t & 1, npar = par ^ 1;

        // ---- acc init from prefetched xz (bias folded in by gemm_k)
        v4f acc[4];
#pragma unroll
        for (int j = 0; j < 4; j++)
#pragma unroll
            for (int q = 0; q < 4; q++) acc[j][q] = b2f(xzp[j * 4 + q]);

        // ---- issue xz prefetch for t+1 (overlaps MFMA + poll)
        {
            int tn = (t < 511) ? t + 1 : t;
#pragma unroll
            for (int j = 0; j < 4; j++)
#pragma unroll
                for (int q = 0; q < 4; q++)
                    xzp[j * 4 + q] = xz[(long)(tn * 256 + bt + lq * 4 + q) * 1024 +
                                        (gate * 256 + r * 128 + hblk + j * 16 + l15)];
        }

        // ---- pre-poll MFMA: own K-half (h written by OWN update last step)
#pragma unroll
        for (int ko = 0; ko < 4; ko++) {
            int ks = r * 4 + ko;
            v8s a = *(const v8s*)&hlds[l15][(ks * 32 + lq * 8) ^ ((l15 & 7) * 8)];
#pragma unroll
            for (int j = 0; j < 4; j++)
                acc[j] = __builtin_amdgcn_mfma_f32_16x16x32_bf16(a, bw[j][ks], acc[j], 0, 0, 0);
        }

        // ---- poll peer flag (acquire: every load invalidates -> never stale)
        if (!dead) {
            const unsigned int want = (unsigned int)(t + 1);
            int guard = 0;
            while (__hip_atomic_load(&flg[((par * 16 + cluster) * 2 + p) * 32],
                                     __ATOMIC_ACQUIRE, __HIP_MEMORY_SCOPE_AGENT) != want) {
                __builtin_amdgcn_s_sleep(1);
                if (++guard > (1 << 14)) { dead = 1; break; }
            }
        }
        // ---- read peer half (plain loads; fresh after acquire-inv), scatter to LDS
        {
            int pb = ((par * 16 + cluster) * 2 + p) * 1024 + row * 64 + (tid & 31) * 2;
            unsigned int w0 = hd32[pb], w1 = hd32[pb + 1];
            u16x4 pv;
            pv[0] = (unsigned short)(w0 & 0xffffu);
            pv[1] = (unsigned short)(w0 >> 16);
            pv[2] = (unsigned short)(w1 & 0xffffu);
            pv[3] = (unsigned short)(w1 >> 16);
            *(u16x4*)&hlds[row][(p * 128 + hid0) ^ swz] = pv;
        }
        __syncthreads();   // A: peer half visible to all waves

        // ---- post-poll MFMA: peer K-half
#pragma unroll
        for (int ko = 0; ko < 4; ko++) {
            int ks = p * 4 + ko;
            v8s a = *(const v8s*)&hlds[l15][(ks * 32 + lq * 8) ^ ((l15 & 7) * 8)];
#pragma unroll
            for (int j = 0; j < 4; j++)
                acc[j] = __builtin_amdgcn_mfma_f32_16x16x32_bf16(a, bw[j][ks], acc[j], 0, 0, 0);
        }
        // gate-major z exchange across waves via LDS
#pragma unroll
        for (int j = 0; j < 4; j++)
#pragma unroll
            for (int q = 0; q < 4; q++)
                zlds[gate][lq * 4 + q][hblk + j * 16 + l15] = acc[j][q];
        __syncthreads();   // B: zlds complete; all hlds MFMA reads done

        // ---- gates + state update + publish + hs history (4 consecutive hid)
        {
            v4f z0 = *(const v4f*)&zlds[0][row][hid0];
            v4f z1 = *(const v4f*)&zlds[1][row][hid0];
            v4f z2 = *(const v4f*)&zlds[2][row][hid0];
            v4f z3 = *(const v4f*)&zlds[3][row][hid0];
            u16x4 hb4, hw4;
#pragma unroll
            for (int i = 0; i < 4; i++) {
                float cm = dn_cur ? 0.f : c[i];
                float cn = sigf(z1[i]) * cm + sigf(z0[i]) * tanh_(z2[i]);
                float h = sigf(z3[i]) * tanh_(cn);
                c[i] = cn;
                hcur[i] = h;
                hb4[i] = f2b(h);
                hw4[i] = dn_nxt ? (unsigned short)0 : hb4[i];
            }
            *(u16x4*)&hlds[row][(r * 128 + hid0) ^ swz] = hw4;   // own half for t+1
            int mb = ((npar * 16 + cluster) * 2 + r) * 1024 + row * 64 + (tid & 31) * 2;
            hd32[mb]     = (unsigned int)hw4[0] | ((unsigned int)hw4[1] << 16);
            hd32[mb + 1] = (unsigned int)hw4[2] | ((unsigned int)hw4[3] << 16);
            long hsb = ((long)(t * 256 + bt + row)) * 128 + r * 64 + (tid & 31) * 2;
            ((unsigned int*)hs)[hsb]     = (unsigned int)hb4[0] | ((unsigned int)hb4[1] << 16);
            ((unsigned int*)hs)[hsb + 1] = (unsigned int)hb4[2] | ((unsigned int)hb4[3] << 16);
        }
        dn_cur = dn_nxt;
        {
            int tn2 = (t + 2 < 512) ? t + 2 : 511;
            dn_nxt = dones[tn2 * 256 + bt + row];
        }
        __syncthreads();   // C: all waves' data stores drained before flag
        if (tid == 0)
            __hip_atomic_store(&flg[((npar * 16 + cluster) * 2 + r) * 32],
                               (unsigned int)(t + 2),
                               __ATOMIC_RELEASE, __HIP_MEMORY_SCOPE_AGENT);
    }

    // c_fin at out elems [0:65536], h_fin at [65536:131072]
#pragma unroll
    for (int i = 0; i < 4; i++) {
        long i1 = (long)(bt + row) * 256 + r * 128 + hid0 + i;
        long i2 = 65536 + i1;
        if (fp32o) {
            ((float*)outv)[i1] = c[i];
            ((float*)outv)[i2] = hcur[i];
        } else {
            ((unsigned short*)outv)[i1] = f2b(c[i]);
            ((unsigned short*)outv)[i2] = f2b(hcur[i]);
        }
    }
}

// ---------------------------------------------------------------------------
// value head: value[r] = v2[r] . Wc3 + bc3   (K=128, N=1)
// ---------------------------------------------------------------------------
__global__ __launch_bounds__(256) void value_k(const unsigned short* __restrict__ V2,
                                               const unsigned short* __restrict__ Wc3T,
                                               const unsigned short* __restrict__ bc3,
                                               void* __restrict__ outv,
                                               const int* __restrict__ dtf) {
    int tid = threadIdx.x;
    int l = tid & 63, w = tid >> 6;
    int fp32o = dtf[0] > DT_THRESH;
    long row = (long)blockIdx.x * 32 + w * 8 + (l >> 3);
    int sub = l & 7;
    const unsigned short* vp = V2 + row * 128 + sub * 16;
    float s = 0.f;
#pragma unroll
    for (int j = 0; j < 16; j++) s += b2f(vp[j]) * b2f(Wc3T[sub * 16 + j]);
    s += __shfl_xor(s, 1);
    s += __shfl_xor(s, 2);
    s += __shfl_xor(s, 4);
    if (sub == 0) {
        float v = s + b2f(bc3[0]);
        if (fp32o) ((float*)outv)[2228224 + row] = v;
        else ((unsigned short*)outv)[2228224 + row] = f2b(v);
    }
}

// ---------------------------------------------------------------------------
// host launcher
// ---------------------------------------------------------------------------
extern "C" void kernel_launch(void* const* d_in, const int* in_sizes, int n_in,
                              void* d_out, int out_size, void* d_ws, size_t ws_size,
                              hipStream_t stream) {
    const void* x             = d_in[0];
    const void* dones_raw     = d_in[1];
    const void* h0c           = d_in[2];
    const void* h0h           = d_in[3];
    const void* We  = d_in[4];
    const unsigned short* be  = (const unsigned short*)d_in[5];
    const void* Wi  = d_in[6];
    const void* Wh  = d_in[7];
    const unsigned short* bl  = (const unsigned short*)d_in[8];
    const void* Wa1 = d_in[9];
    const unsigned short* ba1 = (const unsigned short*)d_in[10];
    const void* Wa2 = d_in[11];
    const unsigned short* ba2 = (const unsigned short*)d_in[12];
    const void* Wa3 = d_in[13];
    const unsigned short* ba3 = (const unsigned short*)d_in[14];
    const void* Wc1 = d_in[15];
    const unsigned short* bc1 = (const unsigned short*)d_in[16];
    const void* Wc2 = d_in[17];
    const unsigned short* bc2 = (const unsigned short*)d_in[18];
    const void* Wc3 = d_in[19];
    const unsigned short* bc3 = (const unsigned short*)d_in[20];
    char* ws = (char*)d_ws;

    // workspace layout (bytes)
    unsigned short* WeT  = (unsigned short*)(ws + 0);          //   131072
    unsigned short* WiT  = (unsigned short*)(ws + 131072);     //   524288
    unsigned short* WhT  = (unsigned short*)(ws + 655360);     //   524288
    unsigned short* Wa1T = (unsigned short*)(ws + 1179648);    //    65536
    unsigned short* Wa2T = (unsigned short*)(ws + 1245184);    //    32768
    unsigned short* Wa3T = (unsigned short*)(ws + 1277952);    //     4096
    unsigned short* Wc1T = (unsigned short*)(ws + 1282048);    //    65536
    unsigned short* Wc2T = (unsigned short*)(ws + 1347584);    //    32768
    unsigned short* Wc3T = (unsigned short*)(ws + 1380352);    //      256
    int*            DT   = (int*)(ws + 1380608);               //       64
    unsigned int*   HB   = (unsigned int*)(ws + 1380672);      //   524288 (flags 8KB + data 256KB)
    int*            DN   = (int*)(ws + 1904960);               //   524288
    unsigned short* XB   = (unsigned short*)(ws + 2429248);    // 67108864
    unsigned short* E    = (unsigned short*)(ws + 69538112);   // 67108864
    unsigned short* XZ   = (unsigned short*)(ws + 136646976);  // 268435456
    unsigned short* HS   = (unsigned short*)(ws + 405082432);  // 67108864 -> ends 472191296
    unsigned short* H1   = XB;                                  // alias (XB dead post-E)
    unsigned short* H2   = XB + 16777216;

    unsigned int* FL = HB;                    // 2048 dwords of flags
    unsigned int* HD = HB + 2048;             // 2x16x2x1024 dwords of h data

    TransArgs ta;
    {
        const void* srcs[9] = {We, Wi, Wh, Wa1, Wa2, Wa3, Wc1, Wc2, Wc3};
        unsigned short* dsts[9] = {WeT, WiT, WhT, Wa1T, Wa2T, Wa3T, Wc1T, Wc2T, Wc3T};
        int Rs[9] = {256, 256, 256, 256, 128, 128, 256, 128, 128};
        int Cs[9] = {256, 1024, 1024, 128, 128, 16, 128, 128, 1};
        int p = 0;
        for (int i = 0; i < 9; i++) {
            ta.src[i] = srcs[i];
            ta.dst[i] = dsts[i];
            ta.R[i] = Rs[i];
            ta.C[i] = Cs[i];
            ta.prefix[i] = p;
            p += Rs[i] * Cs[i];
        }
        ta.prefix[9] = p;
        ta.total = p;  // 690304
    }

    dones_k<<<1, 1024, 0, stream>>>(dones_raw, DN, DT, FL);
    detect_k<<<64, 256, 0, stream>>>((const unsigned short*)x, DT);
    cvt_x_k<<<32768, 256, 0, stream>>>(x, XB, DT);
    trans_kernel<<<2697, 256, 0, stream>>>(ta, DT);

    // E = relu(x @ We + be)            [131072 x 256]
    gemm_k<128, 1, 0><<<dim3(1024, 2), 256, 0, stream>>>(XB, WeT, be, E, 0, nullptr, 256, 256);
    // XZ = E @ Wi + b_lstm             [131072 x 1024]
    gemm_k<128, 0, 0><<<dim3(1024, 8), 256, 0, stream>>>(E, WiT, bl, XZ, 0, nullptr, 1024, 256);
    // LSTM scan -> HS, c_fin, h_fin
    lstm_k<<<32, 512, 0, stream>>>(XZ, DN, h0c, h0h, WhT, FL, HD, HS, d_out, DT);
    // actor head
    gemm_k<128, 2, 0><<<dim3(1024, 1), 256, 0, stream>>>(HS, Wa1T, ba1, H1, 0, nullptr, 128, 256);
    gemm_k<128, 2, 0><<<dim3(1024, 1), 256, 0, stream>>>(H1, Wa2T, ba2, H2, 0, nullptr, 128, 128);
    gemm_k<16, 0, 1><<<dim3(1024, 1), 256, 0, stream>>>(H2, Wa3T, ba3, d_out, 131072, DT, 16, 128);
    // critic head
    gemm_k<128, 2, 0><<<dim3(1024, 1), 256, 0, stream>>>(HS, Wc1T, bc1, H1, 0, nullptr, 128, 256);
    gemm_k<128, 2, 0><<<dim3(1024, 1), 256, 0, stream>>>(H1, Wc2T, bc2, H2, 0, nullptr, 128, 128);
    value_k<<<4096, 256, 0, stream>>>(H2, Wc3T, bc3, d_out, DT);
}

// Round 6
// 5936.631 us; speedup vs baseline: 1.0806x; 1.0806x over previous
//
#include <hip/hip_runtime.h>
#include <stdint.h>

// ---------------------------------------------------------------------------
// EditorActorCritic: embed GEMM -> input-proj GEMM -> clustered LSTM scan ->
// actor/critic head GEMMs.  fp32/bf16 input dtype detected at runtime;
// compute is bf16 MFMA, fp32 accumulate.
// Round-12: XCD-CLAIMED pairing + relaxed-agent exchange.
// Mechanism (rounds 1-5): relaxed agent atomics are coherent WITHIN an XCD
// (L2 = coherence point, atomics bypass L1) but stale ACROSS XCDs; system
// scope risked container hangs; acquire/release agent pays cache maintenance
// per poll (10.8us/step).  Fix: launch 256 candidate WGs; each reads its
// physical XCD (s_getreg XCC_ID) and claims a slot in ITS XCD's bucket
// (device-scope atomicAdd = coherence-point RMW, never stale).  Both ranks
// of a cluster sit in the same bucket -> pair shares an L2 BY CONSTRUCTION
// -> relaxed-agent flag+data exchange is fresh at ~L2 RTT.  Surplus WGs
// linger then rescue-claim starved slots (correctness under any dispatch);
// pairs handshake XCDs and use acquire/release agent iff truly cross-XCD.
// ---------------------------------------------------------------------------

typedef short v8s __attribute__((ext_vector_type(8)));   // 8 x bf16 bits (MFMA A/B frag)
typedef float v4f __attribute__((ext_vector_type(4)));   // MFMA C/D frag
typedef unsigned short u16x4 __attribute__((ext_vector_type(4)));

#define DEV static __device__ __forceinline__
#define DT_THRESH 4096

DEV float b2f(unsigned short h) {
    union { unsigned int u; float f; } v; v.u = ((unsigned int)h) << 16; return v.f;
}
DEV unsigned short f2b(float f) {
    union { float f; unsigned int u; } v; v.f = f;
    unsigned int u = v.u;
    return (unsigned short)((u + 0x7fffu + ((u >> 16) & 1u)) >> 16);
}
DEV float sigf(float x) {
    x = fminf(fmaxf(x, -30.f), 30.f);
    return 1.f / (1.f + __expf(-x));
}
DEV float tanh_(float x) {
    x = fminf(fmaxf(x, -15.f), 15.f);
    float e = __expf(-2.f * x);
    return (1.f - e) / (1.f + e);
}

// exchange-flag load/store: fast (same-XCD) = relaxed agent (L2-coherent,
// cheap); slow (cross-XCD) = acquire/release agent (round-4-proven).
DEV unsigned int fl_ld(const unsigned int* p, int fast) {
    if (fast) return __hip_atomic_load(p, __ATOMIC_RELAXED, __HIP_MEMORY_SCOPE_AGENT);
    return __hip_atomic_load(p, __ATOMIC_ACQUIRE, __HIP_MEMORY_SCOPE_AGENT);
}
DEV void fl_st(unsigned int* p, unsigned int v, int fast) {
    if (fast) __hip_atomic_store(p, v, __ATOMIC_RELAXED, __HIP_MEMORY_SCOPE_AGENT);
    else      __hip_atomic_store(p, v, __ATOMIC_RELEASE, __HIP_MEMORY_SCOPE_AGENT);
}

// ---------------------------------------------------------------------------
// K0a: dones decode (robust int32/bf16/byte) + zero dtype flag + exchange area.
// ---------------------------------------------------------------------------
__global__ __launch_bounds__(1024) void dones_k(const void* __restrict__ raw,
                                                int* __restrict__ dst,
                                                int* __restrict__ dt,
                                                unsigned int* __restrict__ flg) {
    __shared__ int bad_int, bad_bf;
    int tid = threadIdx.x;
    if (tid == 0) { bad_int = 0; bad_bf = 0; dt[0] = 0; }
    // clear flags [0..2047], claim buckets [2048..2055], slot-xcd [2064..2095]
    for (int i = tid; i < 4096; i += 1024) flg[i] = 0u;
    __syncthreads();
    const unsigned int* w = (const unsigned int*)raw;
    int li = 0, lb = 0;
    for (int i = tid; i < 32768; i += 1024) {
        unsigned int v = w[i];
        if (v > 1u) li = 1;
        unsigned int h0 = v & 0xffffu, h1 = v >> 16;
        if ((h0 != 0u && h0 != 0x3f80u) || (h1 != 0u && h1 != 0x3f80u)) lb = 1;
    }
    if (li) atomicOr(&bad_int, 1);
    if (lb) atomicOr(&bad_bf, 1);
    __syncthreads();
    int mode = (!bad_int) ? 0 : ((!bad_bf) ? 1 : 2);
    for (int e = tid; e < 131072; e += 1024) {
        int v;
        if (mode == 0)      v = (((const int*)raw)[e] != 0);
        else if (mode == 1) v = (((const unsigned short*)raw)[e] != 0);
        else                v = (((const unsigned char*)raw)[e] != 0);
        dst[e] = v;
    }
}

// ---------------------------------------------------------------------------
// K0b: float-dtype detect.
// ---------------------------------------------------------------------------
__global__ __launch_bounds__(256) void detect_k(const unsigned short* __restrict__ xr,
                                                int* __restrict__ dt) {
    int tid = blockIdx.x * 256 + threadIdx.x;   // 16384 threads
    int cnt = 0;
    for (int i = tid; i < (1 << 24); i += 16384) {
        unsigned int e = (xr[i] >> 7) & 0xffu;
        cnt += (e >= 140u);
    }
    for (int o = 32; o; o >>= 1) cnt += __shfl_down(cnt, o);
    if ((threadIdx.x & 63) == 0 && cnt) atomicAdd(dt, cnt);
}

// ---------------------------------------------------------------------------
// K0c: x -> bf16 canonical copy.
// ---------------------------------------------------------------------------
__global__ __launch_bounds__(256) void cvt_x_k(const void* __restrict__ xr,
                                               unsigned short* __restrict__ xb,
                                               const int* __restrict__ dt) {
    int fp32i = dt[0] > DT_THRESH;
    long i4 = (long)blockIdx.x * 256 + threadIdx.x;
    if (fp32i) {
        float4 v = ((const float4*)xr)[i4];
        uint2 p;
        p.x = (unsigned int)f2b(v.x) | ((unsigned int)f2b(v.y) << 16);
        p.y = (unsigned int)f2b(v.z) | ((unsigned int)f2b(v.w) << 16);
        ((uint2*)xb)[i4] = p;
    } else {
        ((uint2*)xb)[i4] = ((const uint2*)xr)[i4];
    }
}

// ---------------------------------------------------------------------------
// K0d: transpose (and dtype-convert) weight matrices W[R][C] -> WT[C][R] bf16.
// ---------------------------------------------------------------------------
struct TransArgs {
    const void* src[9];
    unsigned short* dst[9];
    int R[9];
    int C[9];
    int prefix[10];
    int total;
};

__global__ __launch_bounds__(256) void trans_kernel(TransArgs a, const int* __restrict__ dt) {
    int fp32i = dt[0] > DT_THRESH;
    int id = blockIdx.x * 256 + threadIdx.x;
    if (id >= a.total) return;
    int m = 0;
#pragma unroll
    for (int k = 0; k < 9; k++)
        if (id >= a.prefix[k + 1]) m = k + 1;
    int e = id - a.prefix[m];
    int C = a.C[m];
    int r = e / C, c = e % C;
    unsigned short v;
    if (fp32i) v = f2b(((const float*)a.src[m])[e]);
    else       v = ((const unsigned short*)a.src[m])[e];
    a.dst[m][c * a.R[m] + r] = v;
}

// ---------------------------------------------------------------------------
// Generic bf16 GEMM (verified since round 3).
// ---------------------------------------------------------------------------
template <int TN, int ACT, int OM>
__global__ __launch_bounds__(256) void gemm_k(const unsigned short* __restrict__ A,
                                              const unsigned short* __restrict__ BT,
                                              const unsigned short* __restrict__ bias,
                                              void* __restrict__ Cout, long coff,
                                              const int* __restrict__ dtf,
                                              int N, int K) {
    __shared__ unsigned short As[128][40];
    __shared__ unsigned short Bs[TN][40];
    const int tid = threadIdx.x;
    const int l = tid & 63, w = tid >> 6;
    const long m0 = (long)blockIdx.x * 128;
    const int n0 = blockIdx.y * TN;
    constexpr int NRT = (TN == 128) ? 4 : 2;
    constexpr int NCT = (TN == 128) ? 4 : 1;
    int fp32o = (OM == 1) ? (dtf[0] > DT_THRESH) : 0;

    v4f acc[NRT][NCT];
    for (int i = 0; i < NRT; i++)
        for (int j = 0; j < NCT; j++) acc[i][j] = v4f{0.f, 0.f, 0.f, 0.f};

    for (int kc = 0; kc < K; kc += 32) {
        {
            int row = tid >> 1, part = tid & 1;
            const uint4* src = (const uint4*)(A + (m0 + row) * K + kc + part * 16);
            uint4 v0 = src[0], v1 = src[1];
            *(uint4*)&As[row][part * 16] = v0;
            *(uint4*)&As[row][part * 16 + 8] = v1;
        }
        if (TN == 128) {
            int row = tid >> 1, part = tid & 1;
            const uint4* src = (const uint4*)(BT + (long)(n0 + row) * K + kc + part * 16);
            uint4 v0 = src[0], v1 = src[1];
            *(uint4*)&Bs[row][part * 16] = v0;
            *(uint4*)&Bs[row][part * 16 + 8] = v1;
        } else if (tid < 32) {
            int row = tid >> 1, part = tid & 1;
            const uint4* src = (const uint4*)(BT + (long)(n0 + row) * K + kc + part * 16);
            uint4 v0 = src[0], v1 = src[1];
            *(uint4*)&Bs[row][part * 16] = v0;
            *(uint4*)&Bs[row][part * 16 + 8] = v1;
        }
        __syncthreads();

        v8s af[NRT], bf[NCT];
#pragma unroll
        for (int i = 0; i < NRT; i++) {
            int rt = (TN == 128) ? ((w >> 1) * 4 + i) : (w * 2 + i);
            af[i] = *(const v8s*)&As[rt * 16 + (l & 15)][(l >> 4) * 8];
        }
#pragma unroll
        for (int j = 0; j < NCT; j++) {
            int ct = (TN == 128) ? ((w & 1) * 4 + j) : 0;
            bf[j] = *(const v8s*)&Bs[ct * 16 + (l & 15)][(l >> 4) * 8];
        }
#pragma unroll
        for (int i = 0; i < NRT; i++)
#pragma unroll
            for (int j = 0; j < NCT; j++)
                acc[i][j] = __builtin_amdgcn_mfma_f32_16x16x32_bf16(af[i], bf[j], acc[i][j], 0, 0, 0);
        __syncthreads();
    }

#pragma unroll
    for (int j = 0; j < NCT; j++) {
        int ct = (TN == 128) ? ((w & 1) * 4 + j) : 0;
        int col = ct * 16 + (l & 15);
        float bv = b2f(bias[n0 + col]);
#pragma unroll
        for (int i = 0; i < NRT; i++) {
            int rt = (TN == 128) ? ((w >> 1) * 4 + i) : (w * 2 + i);
#pragma unroll
            for (int q = 0; q < 4; q++) {
                long row = m0 + rt * 16 + (l >> 4) * 4 + q;
                float v = acc[i][j][q] + bv;
                if (ACT == 1) v = fmaxf(v, 0.f);
                if (ACT == 2) v = tanh_(v);
                long idx = coff + row * (long)N + n0 + col;
                if (OM == 1 && fp32o) ((float*)Cout)[idx] = v;
                else ((unsigned short*)Cout)[idx] = f2b(v);
            }
        }
    }
}

// ---------------------------------------------------------------------------
// K2: LSTM scan.  16 clusters x 2 ranks; 256 candidate WGs of 512 threads;
// slots claimed per-XCD so each pair shares an L2.  Wh register-pinned
// (128 VGPR/lane).  Exchange: data = relaxed-agent atomics (L1-bypass,
// L2-hit); flag = relaxed-agent (same-XCD) or acq/rel-agent (cross-XCD,
// rescue-only).  Writer: data stores -> __syncthreads (vmcnt drain) ->
// flag store.  Reader: spin one flag word (>=), fence, 8B data read.
// K-loop split around the poll (own half before, peer half after).
// ---------------------------------------------------------------------------
__global__ __launch_bounds__(512, 2) void lstm_k(const unsigned short* __restrict__ xz,   // [512*256][1024]
                                                 const int* __restrict__ dones,           // [512][256] decoded
                                                 const void* __restrict__ h0c,
                                                 const void* __restrict__ h0h,
                                                 const unsigned short* __restrict__ WhT,  // [1024][256]
                                                 unsigned int* __restrict__ flg,          // 4096 dwords
                                                 unsigned int* __restrict__ hd32,         // data: 2x16x2x1024 dw
                                                 unsigned short* __restrict__ hs,         // [512*256][256] (bf16)
                                                 void* __restrict__ outv,
                                                 const int* __restrict__ dtf) {
    __shared__ unsigned short hlds[16][256];   // full-h tile, XOR-swizzled cols
    __shared__ float zlds[4][16][132];         // [gate][row][hid] (+4 pad)
    __shared__ int sslot, sfast;

    const int tid = threadIdx.x;               // 0..511

    // ---- slot claim: bucket per physical XCD (device-scope RMW: coherent)
    unsigned int xcd = 0;
    if (tid == 0) {
        xcd = __builtin_amdgcn_s_getreg(63508) & 7u;   // hwreg(XCC_ID=20,0,32)
        unsigned int idx = atomicAdd(&flg[2048 + xcd], 1u);
        sslot = (idx < 4u) ? (int)(xcd * 4u + idx) : -1;
    }
    __syncthreads();
    int slot = sslot;
    if (slot < 0) {
        // surplus WG: linger ~200us, then rescue-claim any starved slot
        if (tid == 0) {
            for (int it = 0; it < 64; ++it) __builtin_amdgcn_s_sleep(127);
            int got = -1;
            for (int x = 0; x < 8 && got < 0; ++x) {
                unsigned int idx = atomicAdd(&flg[2048 + x], 1u);
                if (idx < 4u) got = (int)(x * 4u + idx);
            }
            sslot = got;
        }
        __syncthreads();
        slot = sslot;
        if (slot < 0) return;
    }
    const int cluster = (slot >> 2) + 8 * ((slot & 3) >> 1);
    const int r = slot & 1;
    const int p = r ^ 1;

    // ---- handshake: publish my XCD; learn peer's; pick protocol
    if (tid == 0) {
        __hip_atomic_store(&flg[2064 + slot], xcd + 1u,
                           __ATOMIC_RELEASE, __HIP_MEMORY_SCOPE_AGENT);
        int pslot = (cluster & 7) * 4 + ((cluster >> 3) << 1) + p;
        unsigned int px = 0; int g = 0;
        do {
            px = __hip_atomic_load(&flg[2064 + pslot],
                                   __ATOMIC_ACQUIRE, __HIP_MEMORY_SCOPE_AGENT);
            if (px) break;
            __builtin_amdgcn_s_sleep(16);
        } while (++g < (1 << 16));
        sfast = px ? (((px - 1u) == xcd) ? 1 : 0) : -1;   // -1: peer missing
    }
    __syncthreads();
    const int fastp = (sfast == 1);
    int dead = (sfast < 0);

    const int l = tid & 63;
    const int w = tid >> 6;                    // wave 0..7
    const int bt = cluster * 16;
    const int fp32o = dtf[0] > DT_THRESH;
    const int gate = w & 3;
    const int hblk = (w >> 2) * 64;            // hid sub-block within rank's 128
    const int l15 = l & 15;
    const int lq = l >> 4;
    const int row = tid >> 5;                  // update-path row (0..15)
    const int hid0 = (tid & 31) * 4;           // rank-local hid base (0..124)
    const int swz = (row & 7) * 8;

    // ---- Wh B-fragments -> registers (once): bw[j][ks], 128 VGPRs
    v8s bw[4][8];
#pragma unroll
    for (int j = 0; j < 4; j++) {
        const unsigned short* wp =
            WhT + (long)(gate * 256 + r * 128 + hblk + j * 16 + l15) * 256 + lq * 8;
#pragma unroll
        for (int ks = 0; ks < 8; ks++) bw[j][ks] = *(const v8s*)(wp + ks * 32);
    }

    // ---- init: c/h0 load (4 consecutive hid at one row), masked publish
    float c[4], hcur[4] = {0.f, 0.f, 0.f, 0.f};
    int dn_cur = dones[bt + row];
    int dn_nxt = dones[256 + bt + row];
    {
        u16x4 hw4;
#pragma unroll
        for (int i = 0; i < 4; i++) {
            long idx = (long)(bt + row) * 256 + r * 128 + hid0 + i;
            c[i] = fp32o ? ((const float*)h0c)[idx] : b2f(((const unsigned short*)h0c)[idx]);
            float h0 = fp32o ? ((const float*)h0h)[idx] : b2f(((const unsigned short*)h0h)[idx]);
            hw4[i] = dn_cur ? (unsigned short)0 : f2b(h0);
        }
        *(u16x4*)&hlds[row][(r * 128 + hid0) ^ swz] = hw4;
        int mb = ((0 * 16 + cluster) * 2 + r) * 1024 + row * 64 + (tid & 31) * 2;
        unsigned long long dv = (unsigned long long)((unsigned int)hw4[0] | ((unsigned int)hw4[1] << 16)) |
                                ((unsigned long long)((unsigned int)hw4[2] | ((unsigned int)hw4[3] << 16)) << 32);
        __hip_atomic_store((unsigned long long*)&hd32[mb], dv,
                           __ATOMIC_RELAXED, __HIP_MEMORY_SCOPE_AGENT);
    }
    // xz prefetch for t=0 (per-wave MFMA-C-layout mapping)
    unsigned short xzp[16];
#pragma unroll
    for (int j = 0; j < 4; j++)
#pragma unroll
        for (int q = 0; q < 4; q++)
            xzp[j * 4 + q] = xz[(long)(bt + lq * 4 + q) * 1024 +
                                (gate * 256 + r * 128 + hblk + j * 16 + l15)];
    __syncthreads();   // data stores drained (vmcnt) + hlds visible
    if (tid == 0)
        fl_st(&flg[((0 * 16 + cluster) * 2 + r) * 32], 1u, fastp);

    for (int t = 0; t < 512; t++) {
        const int par = t & 1, npar = par ^ 1;

        // ---- acc init from prefetched xz (bias folded in by gemm_k)
        v4f acc[4];
#pragma unroll
        for (int j = 0; j < 4; j++)
#pragma unroll
            for (int q = 0; q < 4; q++) acc[j][q] = b2f(xzp[j * 4 + q]);

        // ---- issue xz prefetch for t+1 (overlaps MFMA + poll)
        {
            int tn = (t < 511) ? t + 1 : t;
#pragma unroll
            for (int j = 0; j < 4; j++)
#pragma unroll
                for (int q = 0; q < 4; q++)
                    xzp[j * 4 + q] = xz[(long)(tn * 256 + bt + lq * 4 + q) * 1024 +
                                        (gate * 256 + r * 128 + hblk + j * 16 + l15)];
        }

        // ---- pre-poll MFMA: own K-half (h written by OWN update last step)
#pragma unroll
        for (int ko = 0; ko < 4; ko++) {
            int ks = r * 4 + ko;
            v8s a = *(const v8s*)&hlds[l15][(ks * 32 + lq * 8) ^ ((l15 & 7) * 8)];
#pragma unroll
            for (int j = 0; j < 4; j++)
                acc[j] = __builtin_amdgcn_mfma_f32_16x16x32_bf16(a, bw[j][ks], acc[j], 0, 0, 0);
        }

        // ---- poll peer flag (same-L2: fresh at ~L2 RTT)
        if (!dead) {
            const unsigned int want = (unsigned int)(t + 1);
            int guard = 0;
            while (fl_ld(&flg[((par * 16 + cluster) * 2 + p) * 32], fastp) < want) {
                if (++guard > (1 << 14)) { dead = 1; break; }
            }
        }
        __atomic_signal_fence(__ATOMIC_ACQ_REL);   // compiler-only: no hoisting
        // ---- read peer half (8B agent-scope load: L1-bypass), scatter to LDS
        {
            int pb = ((par * 16 + cluster) * 2 + p) * 1024 + row * 64 + (tid & 31) * 2;
            unsigned long long pv64 =
                __hip_atomic_load((const unsigned long long*)&hd32[pb],
                                  __ATOMIC_RELAXED, __HIP_MEMORY_SCOPE_AGENT);
            unsigned int w0 = (unsigned int)pv64, w1 = (unsigned int)(pv64 >> 32);
            u16x4 pv;
            pv[0] = (unsigned short)(w0 & 0xffffu);
            pv[1] = (unsigned short)(w0 >> 16);
            pv[2] = (unsigned short)(w1 & 0xffffu);
            pv[3] = (unsigned short)(w1 >> 16);
            *(u16x4*)&hlds[row][(p * 128 + hid0) ^ swz] = pv;
        }
        __syncthreads();   // A: peer half visible to all waves

        // ---- post-poll MFMA: peer K-half
#pragma unroll
        for (int ko = 0; ko < 4; ko++) {
            int ks = p * 4 + ko;
            v8s a = *(const v8s*)&hlds[l15][(ks * 32 + lq * 8) ^ ((l15 & 7) * 8)];
#pragma unroll
            for (int j = 0; j < 4; j++)
                acc[j] = __builtin_amdgcn_mfma_f32_16x16x32_bf16(a, bw[j][ks], acc[j], 0, 0, 0);
        }
        // gate-major z exchange across waves via LDS
#pragma unroll
        for (int j = 0; j < 4; j++)
#pragma unroll
            for (int q = 0; q < 4; q++)
                zlds[gate][lq * 4 + q][hblk + j * 16 + l15] = acc[j][q];
        __syncthreads();   // B: zlds complete; all hlds MFMA reads done

        // ---- gates + state update + publish + hs history (4 consecutive hid)
        {
            v4f z0 = *(const v4f*)&zlds[0][row][hid0];
            v4f z1 = *(const v4f*)&zlds[1][row][hid0];
            v4f z2 = *(const v4f*)&zlds[2][row][hid0];
            v4f z3 = *(const v4f*)&zlds[3][row][hid0];
            u16x4 hb4, hw4;
#pragma unroll
            for (int i = 0; i < 4; i++) {
                float cm = dn_cur ? 0.f : c[i];
                float cn = sigf(z1[i]) * cm + sigf(z0[i]) * tanh_(z2[i]);
                float h = sigf(z3[i]) * tanh_(cn);
                c[i] = cn;
                hcur[i] = h;
                hb4[i] = f2b(h);
                hw4[i] = dn_nxt ? (unsigned short)0 : hb4[i];
            }
            *(u16x4*)&hlds[row][(r * 128 + hid0) ^ swz] = hw4;   // own half for t+1
            int mb = ((npar * 16 + cluster) * 2 + r) * 1024 + row * 64 + (tid & 31) * 2;
            unsigned long long dv = (unsigned long long)((unsigned int)hw4[0] | ((unsigned int)hw4[1] << 16)) |
                                    ((unsigned long long)((unsigned int)hw4[2] | ((unsigned int)hw4[3] << 16)) << 32);
            __hip_atomic_store((unsigned long long*)&hd32[mb], dv,
                               __ATOMIC_RELAXED, __HIP_MEMORY_SCOPE_AGENT);
            long hsb = ((long)(t * 256 + bt + row)) * 128 + r * 64 + (tid & 31) * 2;
            ((unsigned int*)hs)[hsb]     = (unsigned int)hb4[0] | ((unsigned int)hb4[1] << 16);
            ((unsigned int*)hs)[hsb + 1] = (unsigned int)hb4[2] | ((unsigned int)hb4[3] << 16);
        }
        dn_cur = dn_nxt;
        {
            int tn2 = (t + 2 < 512) ? t + 2 : 511;
            dn_nxt = dones[tn2 * 256 + bt + row];
        }
        __syncthreads();   // C: all waves' data stores drained before flag
        if (tid == 0)
            fl_st(&flg[((npar * 16 + cluster) * 2 + r) * 32],
                  (unsigned int)(t + 2), fastp);
    }

    // c_fin at out elems [0:65536], h_fin at [65536:131072]
#pragma unroll
    for (int i = 0; i < 4; i++) {
        long i1 = (long)(bt + row) * 256 + r * 128 + hid0 + i;
        long i2 = 65536 + i1;
        if (fp32o) {
            ((float*)outv)[i1] = c[i];
            ((float*)outv)[i2] = hcur[i];
        } else {
            ((unsigned short*)outv)[i1] = f2b(c[i]);
            ((unsigned short*)outv)[i2] = f2b(hcur[i]);
        }
    }
}

// ---------------------------------------------------------------------------
// value head: value[r] = v2[r] . Wc3 + bc3   (K=128, N=1)
// ---------------------------------------------------------------------------
__global__ __launch_bounds__(256) void value_k(const unsigned short* __restrict__ V2,
                                               const unsigned short* __restrict__ Wc3T,
                                               const unsigned short* __restrict__ bc3,
                                               void* __restrict__ outv,
                                               const int* __restrict__ dtf) {
    int tid = threadIdx.x;
    int l = tid & 63, w = tid >> 6;
    int fp32o = dtf[0] > DT_THRESH;
    long row = (long)blockIdx.x * 32 + w * 8 + (l >> 3);
    int sub = l & 7;
    const unsigned short* vp = V2 + row * 128 + sub * 16;
    float s = 0.f;
#pragma unroll
    for (int j = 0; j < 16; j++) s += b2f(vp[j]) * b2f(Wc3T[sub * 16 + j]);
    s += __shfl_xor(s, 1);
    s += __shfl_xor(s, 2);
    s += __shfl_xor(s, 4);
    if (sub == 0) {
        float v = s + b2f(bc3[0]);
        if (fp32o) ((float*)outv)[2228224 + row] = v;
        else ((unsigned short*)outv)[2228224 + row] = f2b(v);
    }
}

// ---------------------------------------------------------------------------
// host launcher
// ---------------------------------------------------------------------------
extern "C" void kernel_launch(void* const* d_in, const int* in_sizes, int n_in,
                              void* d_out, int out_size, void* d_ws, size_t ws_size,
                              hipStream_t stream) {
    const void* x             = d_in[0];
    const void* dones_raw     = d_in[1];
    const void* h0c           = d_in[2];
    const void* h0h           = d_in[3];
    const void* We  = d_in[4];
    const unsigned short* be  = (const unsigned short*)d_in[5];
    const void* Wi  = d_in[6];
    const void* Wh  = d_in[7];
    const unsigned short* bl  = (const unsigned short*)d_in[8];
    const void* Wa1 = d_in[9];
    const unsigned short* ba1 = (const unsigned short*)d_in[10];
    const void* Wa2 = d_in[11];
    const unsigned short* ba2 = (const unsigned short*)d_in[12];
    const void* Wa3 = d_in[13];
    const unsigned short* ba3 = (const unsigned short*)d_in[14];
    const void* Wc1 = d_in[15];
    const unsigned short* bc1 = (const unsigned short*)d_in[16];
    const void* Wc2 = d_in[17];
    const unsigned short* bc2 = (const unsigned short*)d_in[18];
    const void* Wc3 = d_in[19];
    const unsigned short* bc3 = (const unsigned short*)d_in[20];
    char* ws = (char*)d_ws;

    // workspace layout (bytes)
    unsigned short* WeT  = (unsigned short*)(ws + 0);          //   131072
    unsigned short* WiT  = (unsigned short*)(ws + 131072);     //   524288
    unsigned short* WhT  = (unsigned short*)(ws + 655360);     //   524288
    unsigned short* Wa1T = (unsigned short*)(ws + 1179648);    //    65536
    unsigned short* Wa2T = (unsigned short*)(ws + 1245184);    //    32768
    unsigned short* Wa3T = (unsigned short*)(ws + 1277952);    //     4096
    unsigned short* Wc1T = (unsigned short*)(ws + 1282048);    //    65536
    unsigned short* Wc2T = (unsigned short*)(ws + 1347584);    //    32768
    unsigned short* Wc3T = (unsigned short*)(ws + 1380352);    //      256
    int*            DT   = (int*)(ws + 1380608);               //       64
    unsigned int*   HB   = (unsigned int*)(ws + 1380672);      //   524288 (flags 16KB + data 256KB)
    int*            DN   = (int*)(ws + 1904960);               //   524288
    unsigned short* XB   = (unsigned short*)(ws + 2429248);    // 67108864
    unsigned short* E    = (unsigned short*)(ws + 69538112);   // 67108864
    unsigned short* XZ   = (unsigned short*)(ws + 136646976);  // 268435456
    unsigned short* HS   = (unsigned short*)(ws + 405082432);  // 67108864 -> ends 472191296
    unsigned short* H1   = XB;                                  // alias (XB dead post-E)
    unsigned short* H2   = XB + 16777216;

    unsigned int* FL = HB;                    // 4096 dwords: flags + claim + slotxcd
    unsigned int* HD = HB + 4096;             // 2x16x2x1024 dwords of h data

    TransArgs ta;
    {
        const void* srcs[9] = {We, Wi, Wh, Wa1, Wa2, Wa3, Wc1, Wc2, Wc3};
        unsigned short* dsts[9] = {WeT, WiT, WhT, Wa1T, Wa2T, Wa3T, Wc1T, Wc2T, Wc3T};
        int Rs[9] = {256, 256, 256, 256, 128, 128, 256, 128, 128};
        int Cs[9] = {256, 1024, 1024, 128, 128, 16, 128, 128, 1};
        int p = 0;
        for (int i = 0; i < 9; i++) {
            ta.src[i] = srcs[i];
            ta.dst[i] = dsts[i];
            ta.R[i] = Rs[i];
            ta.C[i] = Cs[i];
            ta.prefix[i] = p;
            p += Rs[i] * Cs[i];
        }
        ta.prefix[9] = p;
        ta.total = p;  // 690304
    }

    dones_k<<<1, 1024, 0, stream>>>(dones_raw, DN, DT, FL);
    detect_k<<<64, 256, 0, stream>>>((const unsigned short*)x, DT);
    cvt_x_k<<<32768, 256, 0, stream>>>(x, XB, DT);
    trans_kernel<<<2697, 256, 0, stream>>>(ta, DT);

    // E = relu(x @ We + be)            [131072 x 256]
    gemm_k<128, 1, 0><<<dim3(1024, 2), 256, 0, stream>>>(XB, WeT, be, E, 0, nullptr, 256, 256);
    // XZ = E @ Wi + b_lstm             [131072 x 1024]
    gemm_k<128, 0, 0><<<dim3(1024, 8), 256, 0, stream>>>(E, WiT, bl, XZ, 0, nullptr, 1024, 256);
    // LSTM scan -> HS, c_fin, h_fin   (256 candidates, 32 claim slots)
    lstm_k<<<256, 512, 0, stream>>>(XZ, DN, h0c, h0h, WhT, FL, HD, HS, d_out, DT);
    // actor head
    gemm_k<128, 2, 0><<<dim3(1024, 1), 256, 0, stream>>>(HS, Wa1T, ba1, H1, 0, nullptr, 128, 256);
    gemm_k<128, 2, 0><<<dim3(1024, 1), 256, 0, stream>>>(H1, Wa2T, ba2, H2, 0, nullptr, 128, 128);
    gemm_k<16, 0, 1><<<dim3(1024, 1), 256, 0, stream>>>(H2, Wa3T, ba3, d_out, 131072, DT, 16, 128);
    // critic head
    gemm_k<128, 2, 0><<<dim3(1024, 1), 256, 0, stream>>>(HS, Wc1T, bc1, H1, 0, nullptr, 128, 256);
    gemm_k<128, 2, 0><<<dim3(1024, 1), 256, 0, stream>>>(H1, Wc2T, bc2, H2, 0, nullptr, 128, 128);
    value_k<<<4096, 256, 0, stream>>>(H2, Wc3T, bc3, d_out, DT);
}

// Round 7
// 5846.836 us; speedup vs baseline: 1.0971x; 1.0154x over previous
//
#include <hip/hip_runtime.h>
#include <stdint.h>

// ---------------------------------------------------------------------------
// EditorActorCritic: embed GEMM -> input-proj GEMM -> clustered LSTM scan ->
// actor/critic head GEMMs.  fp32/bf16 input dtype detected at runtime;
// compute is bf16 MFMA, fp32 accumulate.
// Round-13: DE-CONTENDED POLL.  Round-4 (acq/rel) and round-6 (relaxed)
// agent-scope flag exchanges both measured ~10us/step -> the protocol
// flavor wasn't the cost; the 512-thread spin on ONE flag dword was
// (thousands-deep same-line probe storm delays the writer's store).  Fix:
// tid0 alone polls, everyone else waits at a barrier, then all threads do
// one 8B data read.  All memory ops byte-identical to round 6 (correct,
// uniform timing).  XCD-claimed pairing kept: both ranks of a cluster claim
// slots in the same physical XCD's bucket (s_getreg XCC_ID + device atomicAdd),
// so the flag/data round trip is as local as the fabric allows.
// ---------------------------------------------------------------------------

typedef short v8s __attribute__((ext_vector_type(8)));   // 8 x bf16 bits (MFMA A/B frag)
typedef float v4f __attribute__((ext_vector_type(4)));   // MFMA C/D frag
typedef unsigned short u16x4 __attribute__((ext_vector_type(4)));

#define DEV static __device__ __forceinline__
#define DT_THRESH 4096

DEV float b2f(unsigned short h) {
    union { unsigned int u; float f; } v; v.u = ((unsigned int)h) << 16; return v.f;
}
DEV unsigned short f2b(float f) {
    union { float f; unsigned int u; } v; v.f = f;
    unsigned int u = v.u;
    return (unsigned short)((u + 0x7fffu + ((u >> 16) & 1u)) >> 16);
}
DEV float sigf(float x) {
    x = fminf(fmaxf(x, -30.f), 30.f);
    return 1.f / (1.f + __expf(-x));
}
DEV float tanh_(float x) {
    x = fminf(fmaxf(x, -15.f), 15.f);
    float e = __expf(-2.f * x);
    return (1.f - e) / (1.f + e);
}

// exchange-flag load/store: fast (same-XCD) = relaxed agent; slow
// (cross-XCD rescue pairs) = acquire/release agent.
DEV unsigned int fl_ld(const unsigned int* p, int fast) {
    if (fast) return __hip_atomic_load(p, __ATOMIC_RELAXED, __HIP_MEMORY_SCOPE_AGENT);
    return __hip_atomic_load(p, __ATOMIC_ACQUIRE, __HIP_MEMORY_SCOPE_AGENT);
}
DEV void fl_st(unsigned int* p, unsigned int v, int fast) {
    if (fast) __hip_atomic_store(p, v, __ATOMIC_RELAXED, __HIP_MEMORY_SCOPE_AGENT);
    else      __hip_atomic_store(p, v, __ATOMIC_RELEASE, __HIP_MEMORY_SCOPE_AGENT);
}

// ---------------------------------------------------------------------------
// K0a: dones decode (robust int32/bf16/byte) + zero dtype flag + exchange area.
// ---------------------------------------------------------------------------
__global__ __launch_bounds__(1024) void dones_k(const void* __restrict__ raw,
                                                int* __restrict__ dst,
                                                int* __restrict__ dt,
                                                unsigned int* __restrict__ flg) {
    __shared__ int bad_int, bad_bf;
    int tid = threadIdx.x;
    if (tid == 0) { bad_int = 0; bad_bf = 0; dt[0] = 0; }
    // clear flags [0..2047], claim buckets [2048..2055], slot-xcd [2064..2095]
    for (int i = tid; i < 4096; i += 1024) flg[i] = 0u;
    __syncthreads();
    const unsigned int* w = (const unsigned int*)raw;
    int li = 0, lb = 0;
    for (int i = tid; i < 32768; i += 1024) {
        unsigned int v = w[i];
        if (v > 1u) li = 1;
        unsigned int h0 = v & 0xffffu, h1 = v >> 16;
        if ((h0 != 0u && h0 != 0x3f80u) || (h1 != 0u && h1 != 0x3f80u)) lb = 1;
    }
    if (li) atomicOr(&bad_int, 1);
    if (lb) atomicOr(&bad_bf, 1);
    __syncthreads();
    int mode = (!bad_int) ? 0 : ((!bad_bf) ? 1 : 2);
    for (int e = tid; e < 131072; e += 1024) {
        int v;
        if (mode == 0)      v = (((const int*)raw)[e] != 0);
        else if (mode == 1) v = (((const unsigned short*)raw)[e] != 0);
        else                v = (((const unsigned char*)raw)[e] != 0);
        dst[e] = v;
    }
}

// ---------------------------------------------------------------------------
// K0b: float-dtype detect.
// ---------------------------------------------------------------------------
__global__ __launch_bounds__(256) void detect_k(const unsigned short* __restrict__ xr,
                                                int* __restrict__ dt) {
    int tid = blockIdx.x * 256 + threadIdx.x;   // 16384 threads
    int cnt = 0;
    for (int i = tid; i < (1 << 24); i += 16384) {
        unsigned int e = (xr[i] >> 7) & 0xffu;
        cnt += (e >= 140u);
    }
    for (int o = 32; o; o >>= 1) cnt += __shfl_down(cnt, o);
    if ((threadIdx.x & 63) == 0 && cnt) atomicAdd(dt, cnt);
}

// ---------------------------------------------------------------------------
// K0c: x -> bf16 canonical copy.
// ---------------------------------------------------------------------------
__global__ __launch_bounds__(256) void cvt_x_k(const void* __restrict__ xr,
                                               unsigned short* __restrict__ xb,
                                               const int* __restrict__ dt) {
    int fp32i = dt[0] > DT_THRESH;
    long i4 = (long)blockIdx.x * 256 + threadIdx.x;
    if (fp32i) {
        float4 v = ((const float4*)xr)[i4];
        uint2 p;
        p.x = (unsigned int)f2b(v.x) | ((unsigned int)f2b(v.y) << 16);
        p.y = (unsigned int)f2b(v.z) | ((unsigned int)f2b(v.w) << 16);
        ((uint2*)xb)[i4] = p;
    } else {
        ((uint2*)xb)[i4] = ((const uint2*)xr)[i4];
    }
}

// ---------------------------------------------------------------------------
// K0d: transpose (and dtype-convert) weight matrices W[R][C] -> WT[C][R] bf16.
// ---------------------------------------------------------------------------
struct TransArgs {
    const void* src[9];
    unsigned short* dst[9];
    int R[9];
    int C[9];
    int prefix[10];
    int total;
};

__global__ __launch_bounds__(256) void trans_kernel(TransArgs a, const int* __restrict__ dt) {
    int fp32i = dt[0] > DT_THRESH;
    int id = blockIdx.x * 256 + threadIdx.x;
    if (id >= a.total) return;
    int m = 0;
#pragma unroll
    for (int k = 0; k < 9; k++)
        if (id >= a.prefix[k + 1]) m = k + 1;
    int e = id - a.prefix[m];
    int C = a.C[m];
    int r = e / C, c = e % C;
    unsigned short v;
    if (fp32i) v = f2b(((const float*)a.src[m])[e]);
    else       v = ((const unsigned short*)a.src[m])[e];
    a.dst[m][c * a.R[m] + r] = v;
}

// ---------------------------------------------------------------------------
// Generic bf16 GEMM (verified since round 3).
// ---------------------------------------------------------------------------
template <int TN, int ACT, int OM>
__global__ __launch_bounds__(256) void gemm_k(const unsigned short* __restrict__ A,
                                              const unsigned short* __restrict__ BT,
                                              const unsigned short* __restrict__ bias,
                                              void* __restrict__ Cout, long coff,
                                              const int* __restrict__ dtf,
                                              int N, int K) {
    __shared__ unsigned short As[128][40];
    __shared__ unsigned short Bs[TN][40];
    const int tid = threadIdx.x;
    const int l = tid & 63, w = tid >> 6;
    const long m0 = (long)blockIdx.x * 128;
    const int n0 = blockIdx.y * TN;
    constexpr int NRT = (TN == 128) ? 4 : 2;
    constexpr int NCT = (TN == 128) ? 4 : 1;
    int fp32o = (OM == 1) ? (dtf[0] > DT_THRESH) : 0;

    v4f acc[NRT][NCT];
    for (int i = 0; i < NRT; i++)
        for (int j = 0; j < NCT; j++) acc[i][j] = v4f{0.f, 0.f, 0.f, 0.f};

    for (int kc = 0; kc < K; kc += 32) {
        {
            int row = tid >> 1, part = tid & 1;
            const uint4* src = (const uint4*)(A + (m0 + row) * K + kc + part * 16);
            uint4 v0 = src[0], v1 = src[1];
            *(uint4*)&As[row][part * 16] = v0;
            *(uint4*)&As[row][part * 16 + 8] = v1;
        }
        if (TN == 128) {
            int row = tid >> 1, part = tid & 1;
            const uint4* src = (const uint4*)(BT + (long)(n0 + row) * K + kc + part * 16);
            uint4 v0 = src[0], v1 = src[1];
            *(uint4*)&Bs[row][part * 16] = v0;
            *(uint4*)&Bs[row][part * 16 + 8] = v1;
        } else if (tid < 32) {
            int row = tid >> 1, part = tid & 1;
            const uint4* src = (const uint4*)(BT + (long)(n0 + row) * K + kc + part * 16);
            uint4 v0 = src[0], v1 = src[1];
            *(uint4*)&Bs[row][part * 16] = v0;
            *(uint4*)&Bs[row][part * 16 + 8] = v1;
        }
        __syncthreads();

        v8s af[NRT], bf[NCT];
#pragma unroll
        for (int i = 0; i < NRT; i++) {
            int rt = (TN == 128) ? ((w >> 1) * 4 + i) : (w * 2 + i);
            af[i] = *(const v8s*)&As[rt * 16 + (l & 15)][(l >> 4) * 8];
        }
#pragma unroll
        for (int j = 0; j < NCT; j++) {
            int ct = (TN == 128) ? ((w & 1) * 4 + j) : 0;
            bf[j] = *(const v8s*)&Bs[ct * 16 + (l & 15)][(l >> 4) * 8];
        }
#pragma unroll
        for (int i = 0; i < NRT; i++)
#pragma unroll
            for (int j = 0; j < NCT; j++)
                acc[i][j] = __builtin_amdgcn_mfma_f32_16x16x32_bf16(af[i], bf[j], acc[i][j], 0, 0, 0);
        __syncthreads();
    }

#pragma unroll
    for (int j = 0; j < NCT; j++) {
        int ct = (TN == 128) ? ((w & 1) * 4 + j) : 0;
        int col = ct * 16 + (l & 15);
        float bv = b2f(bias[n0 + col]);
#pragma unroll
        for (int i = 0; i < NRT; i++) {
            int rt = (TN == 128) ? ((w >> 1) * 4 + i) : (w * 2 + i);
#pragma unroll
            for (int q = 0; q < 4; q++) {
                long row = m0 + rt * 16 + (l >> 4) * 4 + q;
                float v = acc[i][j][q] + bv;
                if (ACT == 1) v = fmaxf(v, 0.f);
                if (ACT == 2) v = tanh_(v);
                long idx = coff + row * (long)N + n0 + col;
                if (OM == 1 && fp32o) ((float*)Cout)[idx] = v;
                else ((unsigned short*)Cout)[idx] = f2b(v);
            }
        }
    }
}

// ---------------------------------------------------------------------------
// K2: LSTM scan.  16 clusters x 2 ranks; 256 candidate WGs of 512 threads;
// slots claimed per-XCD so each pair shares an XCD.  Wh register-pinned
// (128 VGPR/lane).  Exchange: data = 8B relaxed-agent atomics (coherence
// point, proven correct rounds 4/6); flag = one dword, STORED by tid0 after
// a vmcnt-draining barrier, POLLED BY tid0 ONLY (the round-4/6 regression
// was 512 threads spinning on one line); result broadcast via barrier.
// K-loop split around the poll (own K-half before, peer K-half after).
// ---------------------------------------------------------------------------
__global__ __launch_bounds__(512, 2) void lstm_k(const unsigned short* __restrict__ xz,   // [512*256][1024]
                                                 const int* __restrict__ dones,           // [512][256] decoded
                                                 const void* __restrict__ h0c,
                                                 const void* __restrict__ h0h,
                                                 const unsigned short* __restrict__ WhT,  // [1024][256]
                                                 unsigned int* __restrict__ flg,          // 4096 dwords
                                                 unsigned int* __restrict__ hd32,         // data: 2x16x2x1024 dw
                                                 unsigned short* __restrict__ hs,         // [512*256][256] (bf16)
                                                 void* __restrict__ outv,
                                                 const int* __restrict__ dtf) {
    __shared__ unsigned short hlds[16][256];   // full-h tile, XOR-swizzled cols
    __shared__ float zlds[4][16][132];         // [gate][row][hid] (+4 pad)
    __shared__ int sslot, sfast;

    const int tid = threadIdx.x;               // 0..511

    // ---- slot claim: bucket per physical XCD (device-scope RMW: coherent)
    unsigned int xcd = 0;
    if (tid == 0) {
        xcd = __builtin_amdgcn_s_getreg(63508) & 7u;   // hwreg(XCC_ID=20,0,32)
        unsigned int idx = atomicAdd(&flg[2048 + xcd], 1u);
        sslot = (idx < 4u) ? (int)(xcd * 4u + idx) : -1;
    }
    __syncthreads();
    int slot = sslot;
    if (slot < 0) {
        // surplus WG: linger ~54us, then rescue-claim any starved slot
        if (tid == 0) {
            for (int it = 0; it < 16; ++it) __builtin_amdgcn_s_sleep(127);
            int got = -1;
            for (int x = 0; x < 8 && got < 0; ++x) {
                unsigned int idx = atomicAdd(&flg[2048 + x], 1u);
                if (idx < 4u) got = (int)(x * 4u + idx);
            }
            sslot = got;
        }
        __syncthreads();
        slot = sslot;
        if (slot < 0) return;
    }
    const int cluster = (slot >> 2) + 8 * ((slot & 3) >> 1);
    const int r = slot & 1;
    const int p = r ^ 1;

    // ---- handshake: publish my XCD; learn peer's; pick protocol
    if (tid == 0) {
        __hip_atomic_store(&flg[2064 + slot], xcd + 1u,
                           __ATOMIC_RELEASE, __HIP_MEMORY_SCOPE_AGENT);
        int pslot = (cluster & 7) * 4 + ((cluster >> 3) << 1) + p;
        unsigned int px = 0; int g = 0;
        do {
            px = __hip_atomic_load(&flg[2064 + pslot],
                                   __ATOMIC_ACQUIRE, __HIP_MEMORY_SCOPE_AGENT);
            if (px) break;
            __builtin_amdgcn_s_sleep(16);
        } while (++g < (1 << 16));
        sfast = px ? (((px - 1u) == xcd) ? 1 : 0) : -1;   // -1: peer missing
    }
    __syncthreads();
    const int fastp = (sfast == 1);
    int dead = (sfast < 0);

    const int l = tid & 63;
    const int w = tid >> 6;                    // wave 0..7
    const int bt = cluster * 16;
    const int fp32o = dtf[0] > DT_THRESH;
    const int gate = w & 3;
    const int hblk = (w >> 2) * 64;            // hid sub-block within rank's 128
    const int l15 = l & 15;
    const int lq = l >> 4;
    const int row = tid >> 5;                  // update-path row (0..15)
    const int hid0 = (tid & 31) * 4;           // rank-local hid base (0..124)
    const int swz = (row & 7) * 8;

    // ---- Wh B-fragments -> registers (once): bw[j][ks], 128 VGPRs
    v8s bw[4][8];
#pragma unroll
    for (int j = 0; j < 4; j++) {
        const unsigned short* wp =
            WhT + (long)(gate * 256 + r * 128 + hblk + j * 16 + l15) * 256 + lq * 8;
#pragma unroll
        for (int ks = 0; ks < 8; ks++) bw[j][ks] = *(const v8s*)(wp + ks * 32);
    }

    // ---- init: c/h0 load (4 consecutive hid at one row), masked publish
    float c[4], hcur[4] = {0.f, 0.f, 0.f, 0.f};
    int dn_cur = dones[bt + row];
    int dn_nxt = dones[256 + bt + row];
    {
        u16x4 hw4;
#pragma unroll
        for (int i = 0; i < 4; i++) {
            long idx = (long)(bt + row) * 256 + r * 128 + hid0 + i;
            c[i] = fp32o ? ((const float*)h0c)[idx] : b2f(((const unsigned short*)h0c)[idx]);
            float h0 = fp32o ? ((const float*)h0h)[idx] : b2f(((const unsigned short*)h0h)[idx]);
            hw4[i] = dn_cur ? (unsigned short)0 : f2b(h0);
        }
        *(u16x4*)&hlds[row][(r * 128 + hid0) ^ swz] = hw4;
        int mb = ((0 * 16 + cluster) * 2 + r) * 1024 + row * 64 + (tid & 31) * 2;
        unsigned long long dv = (unsigned long long)((unsigned int)hw4[0] | ((unsigned int)hw4[1] << 16)) |
                                ((unsigned long long)((unsigned int)hw4[2] | ((unsigned int)hw4[3] << 16)) << 32);
        __hip_atomic_store((unsigned long long*)&hd32[mb], dv,
                           __ATOMIC_RELAXED, __HIP_MEMORY_SCOPE_AGENT);
    }
    // xz prefetch for t=0 (per-wave MFMA-C-layout mapping)
    unsigned short xzp[16];
#pragma unroll
    for (int j = 0; j < 4; j++)
#pragma unroll
        for (int q = 0; q < 4; q++)
            xzp[j * 4 + q] = xz[(long)(bt + lq * 4 + q) * 1024 +
                                (gate * 256 + r * 128 + hblk + j * 16 + l15)];
    __syncthreads();   // data stores drained (vmcnt) + hlds visible
    if (tid == 0)
        fl_st(&flg[((0 * 16 + cluster) * 2 + r) * 32], 1u, fastp);

    for (int t = 0; t < 512; t++) {
        const int par = t & 1, npar = par ^ 1;

        // ---- acc init from prefetched xz (bias folded in by gemm_k)
        v4f acc[4];
#pragma unroll
        for (int j = 0; j < 4; j++)
#pragma unroll
            for (int q = 0; q < 4; q++) acc[j][q] = b2f(xzp[j * 4 + q]);

        // ---- issue xz prefetch for t+1 (overlaps MFMA + poll)
        {
            int tn = (t < 511) ? t + 1 : t;
#pragma unroll
            for (int j = 0; j < 4; j++)
#pragma unroll
                for (int q = 0; q < 4; q++)
                    xzp[j * 4 + q] = xz[(long)(tn * 256 + bt + lq * 4 + q) * 1024 +
                                        (gate * 256 + r * 128 + hblk + j * 16 + l15)];
        }

        // ---- pre-poll MFMA: own K-half (h written by OWN update last step)
#pragma unroll
        for (int ko = 0; ko < 4; ko++) {
            int ks = r * 4 + ko;
            v8s a = *(const v8s*)&hlds[l15][(ks * 32 + lq * 8) ^ ((l15 & 7) * 8)];
#pragma unroll
            for (int j = 0; j < 4; j++)
                acc[j] = __builtin_amdgcn_mfma_f32_16x16x32_bf16(a, bw[j][ks], acc[j], 0, 0, 0);
        }

        // ---- poll peer flag: tid0 ONLY (no same-line probe storm)
        if (tid == 0 && !dead) {
            const unsigned int want = (unsigned int)(t + 1);
            int guard = 0;
            while (fl_ld(&flg[((par * 16 + cluster) * 2 + p) * 32], fastp) < want) {
                if (++guard > (1 << 14)) { dead = 1; break; }
            }
        }
        __syncthreads();   // A0: poll complete -> peer data is published
        __atomic_signal_fence(__ATOMIC_ACQ_REL);   // compiler-only: no hoisting
        // ---- read peer half (8B agent-scope load: coherence point), to LDS
        {
            int pb = ((par * 16 + cluster) * 2 + p) * 1024 + row * 64 + (tid & 31) * 2;
            unsigned long long pv64 =
                __hip_atomic_load((const unsigned long long*)&hd32[pb],
                                  __ATOMIC_RELAXED, __HIP_MEMORY_SCOPE_AGENT);
            unsigned int w0 = (unsigned int)pv64, w1 = (unsigned int)(pv64 >> 32);
            u16x4 pv;
            pv[0] = (unsigned short)(w0 & 0xffffu);
            pv[1] = (unsigned short)(w0 >> 16);
            pv[2] = (unsigned short)(w1 & 0xffffu);
            pv[3] = (unsigned short)(w1 >> 16);
            *(u16x4*)&hlds[row][(p * 128 + hid0) ^ swz] = pv;
        }
        __syncthreads();   // A: peer half visible to all waves

        // ---- post-poll MFMA: peer K-half
#pragma unroll
        for (int ko = 0; ko < 4; ko++) {
            int ks = p * 4 + ko;
            v8s a = *(const v8s*)&hlds[l15][(ks * 32 + lq * 8) ^ ((l15 & 7) * 8)];
#pragma unroll
            for (int j = 0; j < 4; j++)
                acc[j] = __builtin_amdgcn_mfma_f32_16x16x32_bf16(a, bw[j][ks], acc[j], 0, 0, 0);
        }
        // gate-major z exchange across waves via LDS
#pragma unroll
        for (int j = 0; j < 4; j++)
#pragma unroll
            for (int q = 0; q < 4; q++)
                zlds[gate][lq * 4 + q][hblk + j * 16 + l15] = acc[j][q];
        __syncthreads();   // B: zlds complete; all hlds MFMA reads done

        // ---- gates + state update + publish + hs history (4 consecutive hid)
        {
            v4f z0 = *(const v4f*)&zlds[0][row][hid0];
            v4f z1 = *(const v4f*)&zlds[1][row][hid0];
            v4f z2 = *(const v4f*)&zlds[2][row][hid0];
            v4f z3 = *(const v4f*)&zlds[3][row][hid0];
            u16x4 hb4, hw4;
#pragma unroll
            for (int i = 0; i < 4; i++) {
                float cm = dn_cur ? 0.f : c[i];
                float cn = sigf(z1[i]) * cm + sigf(z0[i]) * tanh_(z2[i]);
                float h = sigf(z3[i]) * tanh_(cn);
                c[i] = cn;
                hcur[i] = h;
                hb4[i] = f2b(h);
                hw4[i] = dn_nxt ? (unsigned short)0 : hb4[i];
            }
            *(u16x4*)&hlds[row][(r * 128 + hid0) ^ swz] = hw4;   // own half for t+1
            int mb = ((npar * 16 + cluster) * 2 + r) * 1024 + row * 64 + (tid & 31) * 2;
            unsigned long long dv = (unsigned long long)((unsigned int)hw4[0] | ((unsigned int)hw4[1] << 16)) |
                                    ((unsigned long long)((unsigned int)hw4[2] | ((unsigned int)hw4[3] << 16)) << 32);
            __hip_atomic_store((unsigned long long*)&hd32[mb], dv,
                               __ATOMIC_RELAXED, __HIP_MEMORY_SCOPE_AGENT);
            long hsb = ((long)(t * 256 + bt + row)) * 128 + r * 64 + (tid & 31) * 2;
            ((unsigned int*)hs)[hsb]     = (unsigned int)hb4[0] | ((unsigned int)hb4[1] << 16);
            ((unsigned int*)hs)[hsb + 1] = (unsigned int)hb4[2] | ((unsigned int)hb4[3] << 16);
        }
        dn_cur = dn_nxt;
        {
            int tn2 = (t + 2 < 512) ? t + 2 : 511;
            dn_nxt = dones[tn2 * 256 + bt + row];
        }
        __syncthreads();   // C: all waves' data stores drained before flag
        if (tid == 0)
            fl_st(&flg[((npar * 16 + cluster) * 2 + r) * 32],
                  (unsigned int)(t + 2), fastp);
    }

    // c_fin at out elems [0:65536], h_fin at [65536:131072]
#pragma unroll
    for (int i = 0; i < 4; i++) {
        long i1 = (long)(bt + row) * 256 + r * 128 + hid0 + i;
        long i2 = 65536 + i1;
        if (fp32o) {
            ((float*)outv)[i1] = c[i];
            ((float*)outv)[i2] = hcur[i];
        } else {
            ((unsigned short*)outv)[i1] = f2b(c[i]);
            ((unsigned short*)outv)[i2] = f2b(hcur[i]);
        }
    }
}

// ---------------------------------------------------------------------------
// value head: value[r] = v2[r] . Wc3 + bc3   (K=128, N=1)
// ---------------------------------------------------------------------------
__global__ __launch_bounds__(256) void value_k(const unsigned short* __restrict__ V2,
                                               const unsigned short* __restrict__ Wc3T,
                                               const unsigned short* __restrict__ bc3,
                                               void* __restrict__ outv,
                                               const int* __restrict__ dtf) {
    int tid = threadIdx.x;
    int l = tid & 63, w = tid >> 6;
    int fp32o = dtf[0] > DT_THRESH;
    long row = (long)blockIdx.x * 32 + w * 8 + (l >> 3);
    int sub = l & 7;
    const unsigned short* vp = V2 + row * 128 + sub * 16;
    float s = 0.f;
#pragma unroll
    for (int j = 0; j < 16; j++) s += b2f(vp[j]) * b2f(Wc3T[sub * 16 + j]);
    s += __shfl_xor(s, 1);
    s += __shfl_xor(s, 2);
    s += __shfl_xor(s, 4);
    if (sub == 0) {
        float v = s + b2f(bc3[0]);
        if (fp32o) ((float*)outv)[2228224 + row] = v;
        else ((unsigned short*)outv)[2228224 + row] = f2b(v);
    }
}

// ---------------------------------------------------------------------------
// host launcher
// ---------------------------------------------------------------------------
extern "C" void kernel_launch(void* const* d_in, const int* in_sizes, int n_in,
                              void* d_out, int out_size, void* d_ws, size_t ws_size,
                              hipStream_t stream) {
    const void* x             = d_in[0];
    const void* dones_raw     = d_in[1];
    const void* h0c           = d_in[2];
    const void* h0h           = d_in[3];
    const void* We  = d_in[4];
    const unsigned short* be  = (const unsigned short*)d_in[5];
    const void* Wi  = d_in[6];
    const void* Wh  = d_in[7];
    const unsigned short* bl  = (const unsigned short*)d_in[8];
    const void* Wa1 = d_in[9];
    const unsigned short* ba1 = (const unsigned short*)d_in[10];
    const void* Wa2 = d_in[11];
    const unsigned short* ba2 = (const unsigned short*)d_in[12];
    const void* Wa3 = d_in[13];
    const unsigned short* ba3 = (const unsigned short*)d_in[14];
    const void* Wc1 = d_in[15];
    const unsigned short* bc1 = (const unsigned short*)d_in[16];
    const void* Wc2 = d_in[17];
    const unsigned short* bc2 = (const unsigned short*)d_in[18];
    const void* Wc3 = d_in[19];
    const unsigned short* bc3 = (const unsigned short*)d_in[20];
    char* ws = (char*)d_ws;

    // workspace layout (bytes)
    unsigned short* WeT  = (unsigned short*)(ws + 0);          //   131072
    unsigned short* WiT  = (unsigned short*)(ws + 131072);     //   524288
    unsigned short* WhT  = (unsigned short*)(ws + 655360);     //   524288
    unsigned short* Wa1T = (unsigned short*)(ws + 1179648);    //    65536
    unsigned short* Wa2T = (unsigned short*)(ws + 1245184);    //    32768
    unsigned short* Wa3T = (unsigned short*)(ws + 1277952);    //     4096
    unsigned short* Wc1T = (unsigned short*)(ws + 1282048);    //    65536
    unsigned short* Wc2T = (unsigned short*)(ws + 1347584);    //    32768
    unsigned short* Wc3T = (unsigned short*)(ws + 1380352);    //      256
    int*            DT   = (int*)(ws + 1380608);               //       64
    unsigned int*   HB   = (unsigned int*)(ws + 1380672);      //   524288 (flags 16KB + data 256KB)
    int*            DN   = (int*)(ws + 1904960);               //   524288
    unsigned short* XB   = (unsigned short*)(ws + 2429248);    // 67108864
    unsigned short* E    = (unsigned short*)(ws + 69538112);   // 67108864
    unsigned short* XZ   = (unsigned short*)(ws + 136646976);  // 268435456
    unsigned short* HS   = (unsigned short*)(ws + 405082432);  // 67108864 -> ends 472191296
    unsigned short* H1   = XB;                                  // alias (XB dead post-E)
    unsigned short* H2   = XB + 16777216;

    unsigned int* FL = HB;                    // 4096 dwords: flags + claim + slotxcd
    unsigned int* HD = HB + 4096;             // 2x16x2x1024 dwords of h data

    TransArgs ta;
    {
        const void* srcs[9] = {We, Wi, Wh, Wa1, Wa2, Wa3, Wc1, Wc2, Wc3};
        unsigned short* dsts[9] = {WeT, WiT, WhT, Wa1T, Wa2T, Wa3T, Wc1T, Wc2T, Wc3T};
        int Rs[9] = {256, 256, 256, 256, 128, 128, 256, 128, 128};
        int Cs[9] = {256, 1024, 1024, 128, 128, 16, 128, 128, 1};
        int p = 0;
        for (int i = 0; i < 9; i++) {
            ta.src[i] = srcs[i];
            ta.dst[i] = dsts[i];
            ta.R[i] = Rs[i];
            ta.C[i] = Cs[i];
            ta.prefix[i] = p;
            p += Rs[i] * Cs[i];
        }
        ta.prefix[9] = p;
        ta.total = p;  // 690304
    }

    dones_k<<<1, 1024, 0, stream>>>(dones_raw, DN, DT, FL);
    detect_k<<<64, 256, 0, stream>>>((const unsigned short*)x, DT);
    cvt_x_k<<<32768, 256, 0, stream>>>(x, XB, DT);
    trans_kernel<<<2697, 256, 0, stream>>>(ta, DT);

    // E = relu(x @ We + be)            [131072 x 256]
    gemm_k<128, 1, 0><<<dim3(1024, 2), 256, 0, stream>>>(XB, WeT, be, E, 0, nullptr, 256, 256);
    // XZ = E @ Wi + b_lstm             [131072 x 1024]
    gemm_k<128, 0, 0><<<dim3(1024, 8), 256, 0, stream>>>(E, WiT, bl, XZ, 0, nullptr, 1024, 256);
    // LSTM scan -> HS, c_fin, h_fin   (256 candidates, 32 claim slots)
    lstm_k<<<256, 512, 0, stream>>>(XZ, DN, h0c, h0h, WhT, FL, HD, HS, d_out, DT);
    // actor head
    gemm_k<128, 2, 0><<<dim3(1024, 1), 256, 0, stream>>>(HS, Wa1T, ba1, H1, 0, nullptr, 128, 256);
    gemm_k<128, 2, 0><<<dim3(1024, 1), 256, 0, stream>>>(H1, Wa2T, ba2, H2, 0, nullptr, 128, 128);
    gemm_k<16, 0, 1><<<dim3(1024, 1), 256, 0, stream>>>(H2, Wa3T, ba3, d_out, 131072, DT, 16, 128);
    // critic head
    gemm_k<128, 2, 0><<<dim3(1024, 1), 256, 0, stream>>>(HS, Wc1T, bc1, H1, 0, nullptr, 128, 256);
    gemm_k<128, 2, 0><<<dim3(1024, 1), 256, 0, stream>>>(H1, Wc2T, bc2, H2, 0, nullptr, 128, 128);
    value_k<<<4096, 256, 0, stream>>>(H2, Wc3T, bc3, d_out, DT);
}